// Round 12
// baseline (212.988 us; speedup 1.0000x reference)
//
#include <hip/hip_runtime.h>

// ---------------------------------------------------------------------------
// SledAttention: x@Wqkv -> RoPE(q,k) -> softmax(qk^T*scale)v -> @Wout + b
// B=2 N=4096 C=512 H=8 d=64.
// R24: flash occupancy endgame — G=1 per-wave (16 q-rows/wave, R17/R18-
//   verified body, 44 VGPR) x 8-wave shared staging (R23-verified) ->
//   512-thread blocks, grid (32,16,2)=1024 blocks = 4 blocks/CU = 100%
//   occupancy ceiling (LDS 4x32KB=128<=160, threads 2048=max, VGPR<=64
//   allows 8 waves/SIMD). Cost: total staging 2x (256->512MB L2-side) —
//   the structural trade occupancy*amortization=const; this corner never
//   probed. Decisive: occ>45% & flash<75 = win; flash ~90+ = revert R23,
//   flash is at its floor. (512,2) bounds — NOT (.,8): R16 showed forced
//   VGPR ceilings corrupt; natural allocation ~44-50 suffices.
// R23 result: 8-wave stage-sharing -2us (flash 85.5, total 199.7 best);
//   VALU 49->45. Per-SIMD math: VALU floor ~1600cyc/iter, measured ~3200
//   -> still latency-bound, more waves is the only remaining lever.
// R14/R16 lessons: watch WRITE_SIZE (~17MB good, ~300MB spill); no forced
//   register ceilings. R18 lesson: q-split at FLAT occupancy loses 12%.
// R13 heritage: double-buffered K/V LDS; PV on full-rate 16x16x32 via
//   quad-swapped K rows (psi) + permlane32_swap P-merge; bank-balanced
//   16B V reads (conflicts 0). l on VALU adds, shuffle-reduced.
// R11/R12 heritage: fp16 MFMA projections, RoPE fused in gemm1 epilogue,
//   log2(e) folded into Q scale, p=exp2(s) via raw v_exp_f32, 2-way split-K.
// Workspace (55 MB), lifetime-overlapped:
//   [0,8M)    A2x fp16 [8192][512] (gemm1 in); after flash: O2 fp16 (gemm2 in)
//   [8,11M)   B2qkv fp16 [1536][512]   [11,13M) CSSN float2 cos/sin
//   [13,21M)  Q fp16 [16][4096][64] (scale 0.125*log2e folded)
//   [21,29M)  K fp16    [29,37M) V^T fp16 [16][64][4096]
//   [37,53M)  Opart fp16 [2][16][4096][64]   [53,53.5M) lpart fp32
//   [54,54.5M) B2out fp16 [512][512]
// ---------------------------------------------------------------------------

typedef float    floatx4 __attribute__((ext_vector_type(4)));
typedef _Float16 half8   __attribute__((ext_vector_type(8)));
typedef _Float16 half4   __attribute__((ext_vector_type(4)));
typedef unsigned uintx4  __attribute__((ext_vector_type(4)));

// raw v_exp_f32 (1 inst): D = 2^S0. NOT __builtin_exp2f (precise libm path).
__device__ __forceinline__ float fast_exp2(float x) {
#if __has_builtin(__builtin_amdgcn_exp2f)
  return __builtin_amdgcn_exp2f(x);
#else
  float r;
  asm("v_exp_f32 %0, %1" : "=v"(r) : "v"(x));
  return r;
#endif
}

// async global->LDS, 16B/lane; LDS dst = wave-uniform base + lane*16 (m104)
__device__ __forceinline__ void async16(const void* g, void* l) {
  __builtin_amdgcn_global_load_lds(
      (const __attribute__((address_space(1))) void*)g,
      (__attribute__((address_space(3))) void*)l, 16, 0, 0);
}

// v_permlane32_swap_b32: a.hi32lanes <-> b.lo32lanes (one inst, both updated)
__device__ __forceinline__ void pl32swap(unsigned& a, unsigned& b) {
  asm("v_permlane32_swap_b32 %0, %1" : "+v"(a), "+v"(b));
}

// ---------------- fused prep: cast_x | sincos | transpose(Wqkv,Wout) -------
__global__ __launch_bounds__(256) void prep(
    const float* __restrict__ X, const float* __restrict__ pos,
    const float* __restrict__ Wqkv, const float* __restrict__ Wout,
    _Float16* __restrict__ A2, float2* __restrict__ CSSN,
    _Float16* __restrict__ B2qkv, _Float16* __restrict__ B2out) {
  __shared__ float tile[64][65];
  const int bid = blockIdx.x, t = threadIdx.x;
  if (bid < 4096) {            // cast x: [M][512] fp32 -> fp16 (same layout)
    const int i = (bid * 256 + t) * 4;
    const float4 v = *(const float4*)(X + i);
    half4 h;
    h[0] = (_Float16)v.x; h[1] = (_Float16)v.y;
    h[2] = (_Float16)v.z; h[3] = (_Float16)v.w;
    *(half4*)(A2 + i) = h;
  } else if (bid < 5120) {     // cos/sin table
    const int i = (bid - 4096) * 256 + t;
    const float p = pos[i];
    CSSN[i] = make_float2(__cosf(p), __sinf(p));
  } else {                     // transpose W -> B2T [N][512] fp16
    const float* W; _Float16* B2T; int Ncols, bx, by;
    if (bid < 5312) { const int idx = bid - 5120; bx = idx % 24; by = idx / 24;
                      W = Wqkv; B2T = B2qkv; Ncols = 1536; }
    else            { const int idx = bid - 5312; bx = idx % 8;  by = idx / 8;
                      W = Wout; B2T = B2out; Ncols = 512; }
    const int k0 = by * 64, n0 = bx * 64;
    const int lane = t & 63, w = t >> 6;
#pragma unroll 4
    for (int i = 0; i < 16; ++i) {
      const int k = w * 16 + i;
      tile[k][lane] = W[(size_t)(k0 + k) * Ncols + n0 + lane];
    }
    __syncthreads();
#pragma unroll 4
    for (int i = 0; i < 16; ++i) {
      const int n = w * 16 + i;
      B2T[(size_t)(n0 + n) * 512 + k0 + lane] = (_Float16)tile[lane][n];
    }
  }
}

// ---------------- gemm1: fp16 MFMA + fused RoPE epilogue -------------------
// M=8192, N=1536 (q|k|v), K=512 single pass (8 steps of BK=64). Grid (12,64).
__global__ __launch_bounds__(256) void gemm_qkv_rope(
    const _Float16* __restrict__ A2, const _Float16* __restrict__ B2T,
    const float2* __restrict__ CSSN,
    _Float16* __restrict__ Qb, _Float16* __restrict__ Kb,
    _Float16* __restrict__ VT) {
  __shared__ __align__(16) _Float16 ldsA[128 * 64];
  __shared__ __align__(16) _Float16 ldsB[128 * 64];
  __shared__ __align__(16) _Float16 qk_lds[4][16][72];  // per-wave transpose
  const int t = threadIdx.x, w = t >> 6, l = t & 63;
  const int lo = l & 15, hi = l >> 4, sw = lo & 7;
  const int m0 = blockIdx.y << 7, n0 = blockIdx.x << 7;

  const int strow = w * 8 + (l >> 3);
  const int schunk = (l & 7) ^ ((l >> 3) & 7);
  const _Float16* gA = A2 + (size_t)(m0 + strow) * 512 + schunk * 8;
  const _Float16* gB = B2T + (size_t)(n0 + strow) * 512 + schunk * 8;
  _Float16* lA = ldsA + w * 512 + l * 8;
  _Float16* lB = ldsB + w * 512 + l * 8;

  const int mw = (w >> 1) * 64, nw = (w & 1) * 64;

  floatx4 acc[4][4];
#pragma unroll
  for (int mt = 0; mt < 4; ++mt)
#pragma unroll
    for (int nt = 0; nt < 4; ++nt) acc[mt][nt] = (floatx4){0.f, 0.f, 0.f, 0.f};

  for (int ks = 0; ks < 8; ++ks) {
    const int kk = ks * 64;
    __syncthreads();
#pragma unroll
    for (int i = 0; i < 4; ++i) {
      async16(gA + (size_t)i * 32 * 512 + kk, lA + i * 2048);
      async16(gB + (size_t)i * 32 * 512 + kk, lB + i * 2048);
    }
    __syncthreads();  // drains vmcnt: tiles resident
#pragma unroll
    for (int kc = 0; kc < 2; ++kc) {
      const int slot = ((hi + 4 * kc) ^ sw) * 8;
      half8 af[4], bf[4];
#pragma unroll
      for (int mt = 0; mt < 4; ++mt)
        af[mt] = *(const half8*)(ldsA + (mw + mt * 16 + lo) * 64 + slot);
#pragma unroll
      for (int nt = 0; nt < 4; ++nt)
        bf[nt] = *(const half8*)(ldsB + (nw + nt * 16 + lo) * 64 + slot);
#pragma unroll
      for (int mt = 0; mt < 4; ++mt)
#pragma unroll
        for (int nt = 0; nt < 4; ++nt)
          acc[mt][nt] = __builtin_amdgcn_mfma_f32_16x16x32_f16(
              af[mt], bf[nt], acc[mt][nt], 0, 0, 0);
    }
  }

  // ---- fused epilogue: col = bx*128 + nw + nt*16 + lo; dd = nt*16+lo ----
  const int bx = blockIdx.x;
  const int kind = bx >> 2;                     // 0=q, 1=k, 2=v
  const int h = ((bx & 3) << 1) | (nw >> 6);    // head within its 512-block
  if (kind == 2) {
#pragma unroll
    for (int mt = 0; mt < 4; ++mt) {
      const int rowb = m0 + mw + mt * 16 + hi * 4;   // r=0 row; no b-crossing
      const int b = rowb >> 12, nn = rowb & 4095;
#pragma unroll
      for (int nt = 0; nt < 4; ++nt) {
        const int dd = nt * 16 + lo;
        half4 v4;
#pragma unroll
        for (int r = 0; r < 4; ++r) v4[r] = (_Float16)acc[mt][nt][r];
        *(half4*)(VT + ((size_t)((b * 8 + h) * 64 + dd)) * 4096 + nn) = v4;
      }
    }
  } else {
    _Float16* Db = (kind == 0) ? Qb : Kb;
    const float sc = (kind == 0) ? 0.125f * 1.44269504f : 1.0f;  // log2e fold
    _Float16 (*qt_)[72] = qk_lds[w];   // wave-private: no barrier needed
#pragma unroll
    for (int mt = 0; mt < 4; ++mt) {
      // rope -> wave-private LDS tile [row=hi*4+r][col=nt*16+lo]
#pragma unroll
      for (int r = 0; r < 4; ++r) {
        const int row = m0 + mw + mt * 16 + hi * 4 + r;
        const int nn = row & 4095;
        const float2* cp = CSSN + (size_t)nn * 64 + lo;
#pragma unroll
        for (int nt = 0; nt < 4; ++nt) {
          const float2 cs = cp[nt * 16];
          const float x0 = acc[mt][nt][r];
          const float xp = acc[mt][nt ^ 2][r];          // partner dd^32
          const float rot = (nt & 2) ? xp : -xp;        // rotate_half sign
          qt_[hi * 4 + r][nt * 16 + lo] = (_Float16)((x0 * cs.x + rot * cs.y) * sc);
        }
      }
      // wave-lockstep: all 16 rows written; read back contiguous, store 16B
#pragma unroll
      for (int pass = 0; pass < 2; ++pass) {
        const int rr = pass * 8 + (l >> 3);
        const int dcol = (l & 7) * 8;
        const half8 v = *(const half8*)&qt_[rr][dcol];
        const int row = m0 + mw + mt * 16 + rr;
        const int b = row >> 12, nn = row & 4095;
        *(half8*)(Db + ((size_t)((b * 8 + h) * 4096 + nn)) * 64 + dcol) = v;
      }
    }
  }
}

// ---------------- gemm2: fp16, 128x64 tile (512 blocks = 2/CU) -------------
__global__ __launch_bounds__(256) void gemm_out_f16(
    const _Float16* __restrict__ A2, const _Float16* __restrict__ B2T,
    const float* __restrict__ bias, float* __restrict__ C) {
  __shared__ __align__(16) _Float16 ldsA[128 * 64];
  __shared__ __align__(16) _Float16 ldsB[64 * 64];
  const int t = threadIdx.x, w = t >> 6, l = t & 63;
  const int lo = l & 15, hi = l >> 4, sw = lo & 7;
  const int m0 = blockIdx.y << 7, n0 = blockIdx.x << 6;

  const int strow = w * 8 + (l >> 3);
  const int schunk = (l & 7) ^ ((l >> 3) & 7);
  const _Float16* gA = A2 + (size_t)(m0 + strow) * 512 + schunk * 8;
  const _Float16* gB = B2T + (size_t)(n0 + strow) * 512 + schunk * 8;
  _Float16* lA = ldsA + w * 512 + l * 8;
  _Float16* lB = ldsB + w * 512 + l * 8;

  const int mw = (w >> 1) * 64, nw = (w & 1) * 32;

  floatx4 acc[4][2];
#pragma unroll
  for (int mt = 0; mt < 4; ++mt)
#pragma unroll
    for (int nt = 0; nt < 2; ++nt) acc[mt][nt] = (floatx4){0.f, 0.f, 0.f, 0.f};

  for (int ks = 0; ks < 8; ++ks) {
    const int kk = ks * 64;
    __syncthreads();
#pragma unroll
    for (int i = 0; i < 4; ++i)
      async16(gA + (size_t)i * 32 * 512 + kk, lA + i * 2048);
#pragma unroll
    for (int i = 0; i < 2; ++i)
      async16(gB + (size_t)i * 32 * 512 + kk, lB + i * 2048);
    __syncthreads();
#pragma unroll
    for (int kc = 0; kc < 2; ++kc) {
      const int slot = ((hi + 4 * kc) ^ sw) * 8;
      half8 af[4], bf[2];
#pragma unroll
      for (int mt = 0; mt < 4; ++mt)
        af[mt] = *(const half8*)(ldsA + (mw + mt * 16 + lo) * 64 + slot);
#pragma unroll
      for (int nt = 0; nt < 2; ++nt)
        bf[nt] = *(const half8*)(ldsB + (nw + nt * 16 + lo) * 64 + slot);
#pragma unroll
      for (int mt = 0; mt < 4; ++mt)
#pragma unroll
        for (int nt = 0; nt < 2; ++nt)
          acc[mt][nt] = __builtin_amdgcn_mfma_f32_16x16x32_f16(
              af[mt], bf[nt], acc[mt][nt], 0, 0, 0);
    }
  }
#pragma unroll
  for (int mt = 0; mt < 4; ++mt)
#pragma unroll
    for (int r = 0; r < 4; ++r) {
      const int row = m0 + mw + mt * 16 + hi * 4 + r;
#pragma unroll
      for (int nt = 0; nt < 2; ++nt) {
        const int col = n0 + nw + nt * 16 + lo;
        C[(size_t)row * 512 + col] = acc[mt][nt][r] + bias[col];
      }
    }
}

// ---------------- MFMA flash attention, 2-way split-K over KV --------------
// Grid (32 qtiles, 16 bh, 2 splits) = 1024 blocks of 512 threads (8 waves)
// = 4 blocks/CU (100% occupancy ceiling). Each wave owns 16 q-rows (G=1,
// R18-verified body); 8 waves share one 64x64 K/V stage (R23-verified).
__global__ __launch_bounds__(512, 2) void flash_attn(
    const _Float16* __restrict__ Qb, const _Float16* __restrict__ Kb,
    const _Float16* __restrict__ VT, _Float16* __restrict__ Opart,
    float* __restrict__ lpart) {
  __shared__ __align__(16) _Float16 ldsK[2][64 * 64];  // K[j][d], swizzled
  __shared__ __align__(16) _Float16 ldsV[2][64 * 64];  // V^T[d][j], swizzled
  const int t = threadIdx.x;
  const int w = t >> 6, l = t & 63;                    // w = 0..7
  const int lo = l & 15, hi = l >> 4;
  const int sw = lo & 7;
  // psi: quad-swap rows 4..7 <-> 8..11 (bit2<->bit3) for K A-frag reads
  const int lop = (lo & 3) | ((lo & 4) << 1) | ((lo & 8) >> 1);
  const int swk = lop & 7;
  const int bh = blockIdx.y, qt = blockIdx.x, sp = blockIdx.z;

  const int srow = l >> 3;
  const int scol = (l & 7) ^ srow;
  const int goffK = srow * 64 + scol * 8;
  const size_t goffV = (size_t)srow * 4096 + scol * 8;
  const int ldst = l * 8;

  // wave owns q rows qb..qb+15; QK B-frag col = q = qb + lo
  const int qb = qt * 128 + w * 16;
  const _Float16* Qrow = Qb + ((size_t)bh * 4096 + qb + lo) * 64;
  half8 qf[2];
  qf[0] = *(const half8*)(Qrow + hi * 8);        // d 0..31 chunk
  qf[1] = *(const half8*)(Qrow + hi * 8 + 32);   // d 32..63 chunk

  floatx4 acc[4];              // O[q=hi*4+r][d=dt*16+lo]
  float l_s = 0.f;             // lane-partial row sum (q=lo, j in hi-quads)
#pragma unroll
  for (int dt = 0; dt < 4; ++dt) acc[dt] = (floatx4){0.f, 0.f, 0.f, 0.f};

  const _Float16* Kt = Kb + (size_t)bh * 4096 * 64;
  const _Float16* Vt = VT + (size_t)bh * 64 * 4096;

  // 8 waves: wave w stages 8-row chunk w of K and of V (1 async16 each).
  auto stage = [&](int buf, int tt) {
    const _Float16* gK = Kt + (size_t)tt * 4096;
    const _Float16* gV = Vt + tt * 64;
    _Float16* dK = &ldsK[buf][0];
    _Float16* dV = &ldsV[buf][0];
    async16(gK + (size_t)w * 512 + goffK,   dK + w * 512 + ldst);
    async16(gV + (size_t)w * 32768 + goffV, dV + w * 512 + ldst);
  };

  stage(0, sp * 32);
  for (int it = 0; it < 32; ++it) {
    const int cur = it & 1;
    // Single sync point: drains vmcnt (stage(it) loads are a full iteration
    // old -> near-free) and guarantees all waves finished reading buf cur^1.
    __syncthreads();
    if (it != 31) stage(cur ^ 1, sp * 32 + it + 1);
    const _Float16* ldsKc = &ldsK[cur][0];
    const _Float16* ldsVc = &ldsV[cur][0];

    // S^T = K Q^T, with K rows quad-swapped: st[jt][r] = S[j][q=lo],
    // j = jt*16 + psi(hi*4+r) -> each lane holds a CONTIGUOUS j-quad.
    floatx4 st[4];
    __builtin_amdgcn_s_setprio(1);
#pragma unroll
    for (int jt = 0; jt < 4; ++jt) {
      const _Float16* kr = ldsKc + (jt * 16 + lop) * 64;
      const half8 kf0 = *(const half8*)(kr + ((hi ^ swk) * 8));
      const half8 kf1 = *(const half8*)(kr + (((hi + 4) ^ swk) * 8));
      floatx4 z = (floatx4){0.f, 0.f, 0.f, 0.f};
      z = __builtin_amdgcn_mfma_f32_16x16x32_f16(kf0, qf[0], z, 0, 0, 0);
      z = __builtin_amdgcn_mfma_f32_16x16x32_f16(kf1, qf[1], z, 0, 0, 0);
      st[jt] = z;
    }
    __builtin_amdgcn_s_setprio(0);

    // ---- half A: exp/pack jt 0,1 -> paf0; PV with V chunk 0 -------------
    half8 paf0;
    {
      const float a0 = fast_exp2(st[0][0]);
      const float a1 = fast_exp2(st[0][1]);
      const float a2 = fast_exp2(st[0][2]);
      const float a3 = fast_exp2(st[0][3]);
      l_s += (a0 + a1) + (a2 + a3);
      unsigned x0 = __builtin_bit_cast(unsigned, __builtin_amdgcn_cvt_pkrtz(a0, a1));
      unsigned y0 = __builtin_bit_cast(unsigned, __builtin_amdgcn_cvt_pkrtz(a2, a3));
      const float b0 = fast_exp2(st[1][0]);
      const float b1 = fast_exp2(st[1][1]);
      const float b2 = fast_exp2(st[1][2]);
      const float b3 = fast_exp2(st[1][3]);
      l_s += (b0 + b1) + (b2 + b3);
      unsigned x1 = __builtin_bit_cast(unsigned, __builtin_amdgcn_cvt_pkrtz(b0, b1));
      unsigned y1 = __builtin_bit_cast(unsigned, __builtin_amdgcn_cvt_pkrtz(b2, b3));
      pl32swap(x0, x1);
      pl32swap(y0, y1);
      uintx4 u;
      u[0] = x0; u[1] = y0; u[2] = x1; u[3] = y1;
      paf0 = __builtin_bit_cast(half8, u);
    }
    __builtin_amdgcn_s_setprio(1);
#pragma unroll
    for (int dt = 0; dt < 4; ++dt) {
      const _Float16* vrow = ldsVc + (dt * 16 + lo) * 64;
      const half8 vf0 = *(const half8*)(vrow + ((hi ^ sw) * 8));
      acc[dt] = __builtin_amdgcn_mfma_f32_16x16x32_f16(paf0, vf0, acc[dt], 0, 0, 0);
    }
    __builtin_amdgcn_s_setprio(0);

    // ---- half B: exp/pack jt 2,3 -> paf1; PV with V chunk 1 -------------
    half8 paf1;
    {
      const float a0 = fast_exp2(st[2][0]);
      const float a1 = fast_exp2(st[2][1]);
      const float a2 = fast_exp2(st[2][2]);
      const float a3 = fast_exp2(st[2][3]);
      l_s += (a0 + a1) + (a2 + a3);
      unsigned x0 = __builtin_bit_cast(unsigned, __builtin_amdgcn_cvt_pkrtz(a0, a1));
      unsigned y0 = __builtin_bit_cast(unsigned, __builtin_amdgcn_cvt_pkrtz(a2, a3));
      const float b0 = fast_exp2(st[3][0]);
      const float b1 = fast_exp2(st[3][1]);
      const float b2 = fast_exp2(st[3][2]);
      const float b3 = fast_exp2(st[3][3]);
      l_s += (b0 + b1) + (b2 + b3);
      unsigned x1 = __builtin_bit_cast(unsigned, __builtin_amdgcn_cvt_pkrtz(b0, b1));
      unsigned y1 = __builtin_bit_cast(unsigned, __builtin_amdgcn_cvt_pkrtz(b2, b3));
      pl32swap(x0, x1);
      pl32swap(y0, y1);
      uintx4 u;
      u[0] = x0; u[1] = y0; u[2] = x1; u[3] = y1;
      paf1 = __builtin_bit_cast(half8, u);
    }
    __builtin_amdgcn_s_setprio(1);
#pragma unroll
    for (int dt = 0; dt < 4; ++dt) {
      const _Float16* vrow = ldsVc + (dt * 16 + lo) * 64;
      const half8 vf1 = *(const half8*)(vrow + (((4 + hi) ^ sw) * 8));
      acc[dt] = __builtin_amdgcn_mfma_f32_16x16x32_f16(paf1, vf1, acc[dt], 0, 0, 0);
    }
    __builtin_amdgcn_s_setprio(0);
  }

  // epilogue: reduce l across hi-quads (j coverage), store partials.
  _Float16* obase = Opart + ((size_t)(sp * 16 + bh)) * 4096 * 64;
  float*    lbase = lpart + ((size_t)(sp * 16 + bh)) * 4096;
  {
    float v = l_s;
    v += __shfl_xor(v, 16);
    v += __shfl_xor(v, 32);
    if (hi == 0)
      lbase[qb + lo] = v;
  }
#pragma unroll
  for (int r = 0; r < 4; ++r) {
    const int q = qb + hi * 4 + r;
#pragma unroll
    for (int dt = 0; dt < 4; ++dt)
      obase[(size_t)q * 64 + dt * 16 + lo] = (_Float16)acc[dt][r];
  }
}

// ---------------- combine 2 splits: O2 fp16 = (O0+O1)/(l0+l1) --------------
__global__ __launch_bounds__(256) void combine_splits(
    const _Float16* __restrict__ Opart, const float* __restrict__ lpart,
    _Float16* __restrict__ O2) {
  const int idx = blockIdx.x * 256 + threadIdx.x;  // [bh:16][q:4096][d4:16]
  const int d0 = (idx & 15) * 4;
  const int q  = (idx >> 4) & 4095;
  const int bh = idx >> 16;
  const int b = bh >> 3, h = bh & 7;
  const half4 a0 = *(const half4*)(Opart + ((size_t)bh * 4096 + q) * 64 + d0);
  const half4 a1 = *(const half4*)(Opart + ((size_t)(16 + bh) * 4096 + q) * 64 + d0);
  const float lsum = lpart[(size_t)bh * 4096 + q] +
                     lpart[(size_t)(16 + bh) * 4096 + q];
  const float inv = 1.f / lsum;
  half4 o;
#pragma unroll
  for (int i = 0; i < 4; ++i)
    o[i] = (_Float16)(((float)a0[i] + (float)a1[i]) * inv);
  *(half4*)(O2 + ((size_t)(b * 4096 + q)) * 512 + h * 64 + d0) = o;
}

// ---------------------------------------------------------------------------
extern "C" void kernel_launch(void* const* d_in, const int* in_sizes, int n_in,
                              void* d_out, int out_size, void* d_ws, size_t ws_size,
                              hipStream_t stream) {
  const float* x     = (const float*)d_in[0];
  const float* pos   = (const float*)d_in[1];
  const float* w_qkv = (const float*)d_in[2];
  const float* w_out = (const float*)d_in[3];
  const float* b_out = (const float*)d_in[4];
  float* out = (float*)d_out;

  char* ws = (char*)d_ws;
  if (ws_size < (size_t)56 * 1024 * 1024) return;

  const size_t MB = 1024 * 1024;
  _Float16* A2x   = (_Float16*)ws;                     // [0,8M) until gemm1
  _Float16* O2    = (_Float16*)ws;                     // [0,8M) after flash
  _Float16* B2qkv = (_Float16*)(ws + 8 * MB);          // [8,11M)
  float2*   CSSN  = (float2*)(ws + 11 * MB);           // [11,13M)
  _Float16* Qb    = (_Float16*)(ws + 13 * MB);         // [13,21M)
  _Float16* Kb    = (_Float16*)(ws + 21 * MB);         // [21,29M)
  _Float16* VT    = (_Float16*)(ws + 29 * MB);         // [29,37M)
  _Float16* Opart = (_Float16*)(ws + 37 * MB);         // [37,53M)
  float*    lpart = (float*)(ws + 53 * MB);            // [53,53.5M)
  _Float16* B2out = (_Float16*)(ws + 54 * MB);         // [54,54.5M)

  prep<<<5376, 256, 0, stream>>>(x, pos, w_qkv, w_out, A2x, CSSN, B2qkv, B2out);
  gemm_qkv_rope<<<dim3(12, 64), 256, 0, stream>>>(A2x, B2qkv, CSSN, Qb, Kb, VT);
  flash_attn<<<dim3(32, 16, 2), 512, 0, stream>>>(Qb, Kb, VT, Opart, lpart);
  combine_splits<<<4096, 256, 0, stream>>>(Opart, lpart, O2);
  gemm_out_f16<<<dim3(8, 64), 256, 0, stream>>>(O2, B2out, b_out, out);
}

// Round 13
// 196.752 us; speedup vs baseline: 1.0825x; 1.0825x over previous
//
#include <hip/hip_runtime.h>

// ---------------------------------------------------------------------------
// SledAttention: x@Wqkv -> RoPE(q,k) -> softmax(qk^T*scale)v -> @Wout + b
// B=2 N=4096 C=512 H=8 d=64.
// R25: flash blocks 512 -> 1024 threads (16 waves), grid (8,16,2)=256
//   blocks = 1 block/CU = 16 waves/CU = 4 waves/SIMD (SAME residency as
//   R23's 2x8-wave). Total staging halves again (512->256MB L2-side);
//   stage-issue = ONE async16 per lane (waves 0-7 stage K, 8-15 stage V).
//   Per-wave math byte-identical to R23's verified G=2 body.
// R24 verdict (decisive): occupancy 34->47% made flash WORSE (85.5->89.9)
//   -> latency-coverage hypothesis refuted; occupancy lever retired. The
//   only measured win direction is staging amortization (R23: -2us).
// R23: best total 199.7us (flash 85.5, VALU 49->45).
// R14/R16 lessons: watch WRITE_SIZE (~17MB good, ~300MB spill); no forced
//   VGPR ceilings. R18: q-split at flat occupancy loses via 2x staging.
// R13 heritage: double-buffered K/V LDS; PV on full-rate 16x16x32 via
//   quad-swapped K rows (psi) + permlane32_swap P-merge; bank-balanced
//   16B V reads (conflicts 0). l on VALU adds, shuffle-reduced.
// R11/R12 heritage: fp16 MFMA projections, RoPE fused in gemm1 epilogue,
//   log2(e) folded into Q scale, p=exp2(s) via raw v_exp_f32, 2-way split-K.
// Workspace (55 MB), lifetime-overlapped:
//   [0,8M)    A2x fp16 [8192][512] (gemm1 in); after flash: O2 fp16 (gemm2 in)
//   [8,11M)   B2qkv fp16 [1536][512]   [11,13M) CSSN float2 cos/sin
//   [13,21M)  Q fp16 [16][4096][64] (scale 0.125*log2e folded)
//   [21,29M)  K fp16    [29,37M) V^T fp16 [16][64][4096]
//   [37,53M)  Opart fp16 [2][16][4096][64]   [53,53.5M) lpart fp32
//   [54,54.5M) B2out fp16 [512][512]
// ---------------------------------------------------------------------------

typedef float    floatx4 __attribute__((ext_vector_type(4)));
typedef _Float16 half8   __attribute__((ext_vector_type(8)));
typedef _Float16 half4   __attribute__((ext_vector_type(4)));
typedef unsigned uintx4  __attribute__((ext_vector_type(4)));

// raw v_exp_f32 (1 inst): D = 2^S0. NOT __builtin_exp2f (precise libm path).
__device__ __forceinline__ float fast_exp2(float x) {
#if __has_builtin(__builtin_amdgcn_exp2f)
  return __builtin_amdgcn_exp2f(x);
#else
  float r;
  asm("v_exp_f32 %0, %1" : "=v"(r) : "v"(x));
  return r;
#endif
}

// async global->LDS, 16B/lane; LDS dst = wave-uniform base + lane*16 (m104)
__device__ __forceinline__ void async16(const void* g, void* l) {
  __builtin_amdgcn_global_load_lds(
      (const __attribute__((address_space(1))) void*)g,
      (__attribute__((address_space(3))) void*)l, 16, 0, 0);
}

// v_permlane32_swap_b32: a.hi32lanes <-> b.lo32lanes (one inst, both updated)
__device__ __forceinline__ void pl32swap(unsigned& a, unsigned& b) {
  asm("v_permlane32_swap_b32 %0, %1" : "+v"(a), "+v"(b));
}

// ---------------- fused prep: cast_x | sincos | transpose(Wqkv,Wout) -------
__global__ __launch_bounds__(256) void prep(
    const float* __restrict__ X, const float* __restrict__ pos,
    const float* __restrict__ Wqkv, const float* __restrict__ Wout,
    _Float16* __restrict__ A2, float2* __restrict__ CSSN,
    _Float16* __restrict__ B2qkv, _Float16* __restrict__ B2out) {
  __shared__ float tile[64][65];
  const int bid = blockIdx.x, t = threadIdx.x;
  if (bid < 4096) {            // cast x: [M][512] fp32 -> fp16 (same layout)
    const int i = (bid * 256 + t) * 4;
    const float4 v = *(const float4*)(X + i);
    half4 h;
    h[0] = (_Float16)v.x; h[1] = (_Float16)v.y;
    h[2] = (_Float16)v.z; h[3] = (_Float16)v.w;
    *(half4*)(A2 + i) = h;
  } else if (bid < 5120) {     // cos/sin table
    const int i = (bid - 4096) * 256 + t;
    const float p = pos[i];
    CSSN[i] = make_float2(__cosf(p), __sinf(p));
  } else {                     // transpose W -> B2T [N][512] fp16
    const float* W; _Float16* B2T; int Ncols, bx, by;
    if (bid < 5312) { const int idx = bid - 5120; bx = idx % 24; by = idx / 24;
                      W = Wqkv; B2T = B2qkv; Ncols = 1536; }
    else            { const int idx = bid - 5312; bx = idx % 8;  by = idx / 8;
                      W = Wout; B2T = B2out; Ncols = 512; }
    const int k0 = by * 64, n0 = bx * 64;
    const int lane = t & 63, w = t >> 6;
#pragma unroll 4
    for (int i = 0; i < 16; ++i) {
      const int k = w * 16 + i;
      tile[k][lane] = W[(size_t)(k0 + k) * Ncols + n0 + lane];
    }
    __syncthreads();
#pragma unroll 4
    for (int i = 0; i < 16; ++i) {
      const int n = w * 16 + i;
      B2T[(size_t)(n0 + n) * 512 + k0 + lane] = (_Float16)tile[lane][n];
    }
  }
}

// ---------------- gemm1: fp16 MFMA + fused RoPE epilogue -------------------
// M=8192, N=1536 (q|k|v), K=512 single pass (8 steps of BK=64). Grid (12,64).
__global__ __launch_bounds__(256) void gemm_qkv_rope(
    const _Float16* __restrict__ A2, const _Float16* __restrict__ B2T,
    const float2* __restrict__ CSSN,
    _Float16* __restrict__ Qb, _Float16* __restrict__ Kb,
    _Float16* __restrict__ VT) {
  __shared__ __align__(16) _Float16 ldsA[128 * 64];
  __shared__ __align__(16) _Float16 ldsB[128 * 64];
  __shared__ __align__(16) _Float16 qk_lds[4][16][72];  // per-wave transpose
  const int t = threadIdx.x, w = t >> 6, l = t & 63;
  const int lo = l & 15, hi = l >> 4, sw = lo & 7;
  const int m0 = blockIdx.y << 7, n0 = blockIdx.x << 7;

  const int strow = w * 8 + (l >> 3);
  const int schunk = (l & 7) ^ ((l >> 3) & 7);
  const _Float16* gA = A2 + (size_t)(m0 + strow) * 512 + schunk * 8;
  const _Float16* gB = B2T + (size_t)(n0 + strow) * 512 + schunk * 8;
  _Float16* lA = ldsA + w * 512 + l * 8;
  _Float16* lB = ldsB + w * 512 + l * 8;

  const int mw = (w >> 1) * 64, nw = (w & 1) * 64;

  floatx4 acc[4][4];
#pragma unroll
  for (int mt = 0; mt < 4; ++mt)
#pragma unroll
    for (int nt = 0; nt < 4; ++nt) acc[mt][nt] = (floatx4){0.f, 0.f, 0.f, 0.f};

  for (int ks = 0; ks < 8; ++ks) {
    const int kk = ks * 64;
    __syncthreads();
#pragma unroll
    for (int i = 0; i < 4; ++i) {
      async16(gA + (size_t)i * 32 * 512 + kk, lA + i * 2048);
      async16(gB + (size_t)i * 32 * 512 + kk, lB + i * 2048);
    }
    __syncthreads();  // drains vmcnt: tiles resident
#pragma unroll
    for (int kc = 0; kc < 2; ++kc) {
      const int slot = ((hi + 4 * kc) ^ sw) * 8;
      half8 af[4], bf[4];
#pragma unroll
      for (int mt = 0; mt < 4; ++mt)
        af[mt] = *(const half8*)(ldsA + (mw + mt * 16 + lo) * 64 + slot);
#pragma unroll
      for (int nt = 0; nt < 4; ++nt)
        bf[nt] = *(const half8*)(ldsB + (nw + nt * 16 + lo) * 64 + slot);
#pragma unroll
      for (int mt = 0; mt < 4; ++mt)
#pragma unroll
        for (int nt = 0; nt < 4; ++nt)
          acc[mt][nt] = __builtin_amdgcn_mfma_f32_16x16x32_f16(
              af[mt], bf[nt], acc[mt][nt], 0, 0, 0);
    }
  }

  // ---- fused epilogue: col = bx*128 + nw + nt*16 + lo; dd = nt*16+lo ----
  const int bx = blockIdx.x;
  const int kind = bx >> 2;                     // 0=q, 1=k, 2=v
  const int h = ((bx & 3) << 1) | (nw >> 6);    // head within its 512-block
  if (kind == 2) {
#pragma unroll
    for (int mt = 0; mt < 4; ++mt) {
      const int rowb = m0 + mw + mt * 16 + hi * 4;   // r=0 row; no b-crossing
      const int b = rowb >> 12, nn = rowb & 4095;
#pragma unroll
      for (int nt = 0; nt < 4; ++nt) {
        const int dd = nt * 16 + lo;
        half4 v4;
#pragma unroll
        for (int r = 0; r < 4; ++r) v4[r] = (_Float16)acc[mt][nt][r];
        *(half4*)(VT + ((size_t)((b * 8 + h) * 64 + dd)) * 4096 + nn) = v4;
      }
    }
  } else {
    _Float16* Db = (kind == 0) ? Qb : Kb;
    const float sc = (kind == 0) ? 0.125f * 1.44269504f : 1.0f;  // log2e fold
    _Float16 (*qt_)[72] = qk_lds[w];   // wave-private: no barrier needed
#pragma unroll
    for (int mt = 0; mt < 4; ++mt) {
      // rope -> wave-private LDS tile [row=hi*4+r][col=nt*16+lo]
#pragma unroll
      for (int r = 0; r < 4; ++r) {
        const int row = m0 + mw + mt * 16 + hi * 4 + r;
        const int nn = row & 4095;
        const float2* cp = CSSN + (size_t)nn * 64 + lo;
#pragma unroll
        for (int nt = 0; nt < 4; ++nt) {
          const float2 cs = cp[nt * 16];
          const float x0 = acc[mt][nt][r];
          const float xp = acc[mt][nt ^ 2][r];          // partner dd^32
          const float rot = (nt & 2) ? xp : -xp;        // rotate_half sign
          qt_[hi * 4 + r][nt * 16 + lo] = (_Float16)((x0 * cs.x + rot * cs.y) * sc);
        }
      }
      // wave-lockstep: all 16 rows written; read back contiguous, store 16B
#pragma unroll
      for (int pass = 0; pass < 2; ++pass) {
        const int rr = pass * 8 + (l >> 3);
        const int dcol = (l & 7) * 8;
        const half8 v = *(const half8*)&qt_[rr][dcol];
        const int row = m0 + mw + mt * 16 + rr;
        const int b = row >> 12, nn = row & 4095;
        *(half8*)(Db + ((size_t)((b * 8 + h) * 4096 + nn)) * 64 + dcol) = v;
      }
    }
  }
}

// ---------------- gemm2: fp16, 128x64 tile (512 blocks = 2/CU) -------------
__global__ __launch_bounds__(256) void gemm_out_f16(
    const _Float16* __restrict__ A2, const _Float16* __restrict__ B2T,
    const float* __restrict__ bias, float* __restrict__ C) {
  __shared__ __align__(16) _Float16 ldsA[128 * 64];
  __shared__ __align__(16) _Float16 ldsB[64 * 64];
  const int t = threadIdx.x, w = t >> 6, l = t & 63;
  const int lo = l & 15, hi = l >> 4, sw = lo & 7;
  const int m0 = blockIdx.y << 7, n0 = blockIdx.x << 6;

  const int strow = w * 8 + (l >> 3);
  const int schunk = (l & 7) ^ ((l >> 3) & 7);
  const _Float16* gA = A2 + (size_t)(m0 + strow) * 512 + schunk * 8;
  const _Float16* gB = B2T + (size_t)(n0 + strow) * 512 + schunk * 8;
  _Float16* lA = ldsA + w * 512 + l * 8;
  _Float16* lB = ldsB + w * 512 + l * 8;

  const int mw = (w >> 1) * 64, nw = (w & 1) * 32;

  floatx4 acc[4][2];
#pragma unroll
  for (int mt = 0; mt < 4; ++mt)
#pragma unroll
    for (int nt = 0; nt < 2; ++nt) acc[mt][nt] = (floatx4){0.f, 0.f, 0.f, 0.f};

  for (int ks = 0; ks < 8; ++ks) {
    const int kk = ks * 64;
    __syncthreads();
#pragma unroll
    for (int i = 0; i < 4; ++i)
      async16(gA + (size_t)i * 32 * 512 + kk, lA + i * 2048);
#pragma unroll
    for (int i = 0; i < 2; ++i)
      async16(gB + (size_t)i * 32 * 512 + kk, lB + i * 2048);
    __syncthreads();
#pragma unroll
    for (int kc = 0; kc < 2; ++kc) {
      const int slot = ((hi + 4 * kc) ^ sw) * 8;
      half8 af[4], bf[2];
#pragma unroll
      for (int mt = 0; mt < 4; ++mt)
        af[mt] = *(const half8*)(ldsA + (mw + mt * 16 + lo) * 64 + slot);
#pragma unroll
      for (int nt = 0; nt < 2; ++nt)
        bf[nt] = *(const half8*)(ldsB + (nw + nt * 16 + lo) * 64 + slot);
#pragma unroll
      for (int mt = 0; mt < 4; ++mt)
#pragma unroll
        for (int nt = 0; nt < 2; ++nt)
          acc[mt][nt] = __builtin_amdgcn_mfma_f32_16x16x32_f16(
              af[mt], bf[nt], acc[mt][nt], 0, 0, 0);
    }
  }
#pragma unroll
  for (int mt = 0; mt < 4; ++mt)
#pragma unroll
    for (int r = 0; r < 4; ++r) {
      const int row = m0 + mw + mt * 16 + hi * 4 + r;
#pragma unroll
      for (int nt = 0; nt < 2; ++nt) {
        const int col = n0 + nw + nt * 16 + lo;
        C[(size_t)row * 512 + col] = acc[mt][nt][r] + bias[col];
      }
    }
}

// ---------------- MFMA flash attention, 2-way split-K over KV --------------
// Grid (8 qtiles, 16 bh, 2 splits) = 256 blocks of 1024 threads (16 waves)
// = 1 block/CU = 16 waves/CU (4/SIMD, same residency as R23). Sixteen waves
// share one 64x64 K/V stage: waves 0-7 stage K chunk w, waves 8-15 stage V
// chunk w-8 (ONE async16 per lane). Per-wave math identical to R23 (G=2).
__global__ __launch_bounds__(1024, 1) void flash_attn(
    const _Float16* __restrict__ Qb, const _Float16* __restrict__ Kb,
    const _Float16* __restrict__ VT, _Float16* __restrict__ Opart,
    float* __restrict__ lpart) {
  __shared__ __align__(16) _Float16 ldsK[2][64 * 64];  // K[j][d], swizzled
  __shared__ __align__(16) _Float16 ldsV[2][64 * 64];  // V^T[d][j], swizzled
  const int t = threadIdx.x;
  const int w = t >> 6, l = t & 63;                    // w = 0..15
  const int lo = l & 15, hi = l >> 4;
  const int sw = lo & 7;
  // psi: quad-swap rows 4..7 <-> 8..11 (bit2<->bit3) for K A-frag reads
  const int lop = (lo & 3) | ((lo & 4) << 1) | ((lo & 8) >> 1);
  const int swk = lop & 7;
  const int bh = blockIdx.y, qt = blockIdx.x, sp = blockIdx.z;

  const int srow = l >> 3;
  const int scol = (l & 7) ^ srow;
  const int goffK = srow * 64 + scol * 8;
  const size_t goffV = (size_t)srow * 4096 + scol * 8;
  const int ldst = l * 8;

  const _Float16* Qrow = Qb + ((size_t)bh * 4096 + qt * 512 + w * 32 + lo) * 64;
  half8 qf[2][2];
  qf[0][0] = *(const half8*)(Qrow + hi * 8);
  qf[0][1] = *(const half8*)(Qrow + hi * 8 + 32);
  qf[1][0] = *(const half8*)(Qrow + 16 * 64 + hi * 8);
  qf[1][1] = *(const half8*)(Qrow + 16 * 64 + hi * 8 + 32);

  floatx4 acc[2][4];
  float l_s[2] = {0.f, 0.f};   // lane-partial row sums (q=lo, j in hi-quad)
#pragma unroll
  for (int g = 0; g < 2; ++g)
#pragma unroll
    for (int dt = 0; dt < 4; ++dt) acc[g][dt] = (floatx4){0.f, 0.f, 0.f, 0.f};

  const _Float16* Kt = Kb + (size_t)bh * 4096 * 64;
  const _Float16* Vt = VT + (size_t)bh * 64 * 4096;

  // 16 waves: waves 0-7 stage K 8-row chunk w; waves 8-15 stage V chunk w-8.
  auto stage = [&](int buf, int tt) {
    if (w < 8) {
      const _Float16* gK = Kt + (size_t)tt * 4096;
      async16(gK + (size_t)w * 512 + goffK, &ldsK[buf][0] + w * 512 + ldst);
    } else {
      const _Float16* gV = Vt + tt * 64;
      const int wv = w - 8;
      async16(gV + (size_t)wv * 32768 + goffV, &ldsV[buf][0] + wv * 512 + ldst);
    }
  };

  stage(0, sp * 32);
  for (int it = 0; it < 32; ++it) {
    const int cur = it & 1;
    // Single sync point: drains vmcnt (stage(it) loads are a full iteration
    // old -> near-free) and guarantees all waves finished reading buf cur^1.
    __syncthreads();
    if (it != 31) stage(cur ^ 1, sp * 32 + it + 1);
    const _Float16* ldsKc = &ldsK[cur][0];
    const _Float16* ldsVc = &ldsV[cur][0];

    // S^T = K Q^T, with K rows quad-swapped: st[g][jt][r] = S[j][q=lo],
    // j = jt*16 + psi(hi*4+r) -> each lane holds a CONTIGUOUS j-quad.
    floatx4 st[2][4];
    __builtin_amdgcn_s_setprio(1);
#pragma unroll
    for (int jt = 0; jt < 4; ++jt) {
      const _Float16* kr = ldsKc + (jt * 16 + lop) * 64;
      const half8 kf0 = *(const half8*)(kr + ((hi ^ swk) * 8));
      const half8 kf1 = *(const half8*)(kr + (((hi + 4) ^ swk) * 8));
#pragma unroll
      for (int g = 0; g < 2; ++g) {
        floatx4 z = (floatx4){0.f, 0.f, 0.f, 0.f};
        z = __builtin_amdgcn_mfma_f32_16x16x32_f16(kf0, qf[g][0], z, 0, 0, 0);
        z = __builtin_amdgcn_mfma_f32_16x16x32_f16(kf1, qf[g][1], z, 0, 0, 0);
        st[g][jt] = z;
      }
    }
    __builtin_amdgcn_s_setprio(0);

    // ---- half A: exp/pack jt 0,1 -> paf0; PV with V chunk 0 -------------
    half8 paf0[2];
#pragma unroll
    for (int g = 0; g < 2; ++g) {
      const float a0 = fast_exp2(st[g][0][0]);
      const float a1 = fast_exp2(st[g][0][1]);
      const float a2 = fast_exp2(st[g][0][2]);
      const float a3 = fast_exp2(st[g][0][3]);
      l_s[g] += (a0 + a1) + (a2 + a3);
      unsigned x0 = __builtin_bit_cast(unsigned, __builtin_amdgcn_cvt_pkrtz(a0, a1));
      unsigned y0 = __builtin_bit_cast(unsigned, __builtin_amdgcn_cvt_pkrtz(a2, a3));
      const float b0 = fast_exp2(st[g][1][0]);
      const float b1 = fast_exp2(st[g][1][1]);
      const float b2 = fast_exp2(st[g][1][2]);
      const float b3 = fast_exp2(st[g][1][3]);
      l_s[g] += (b0 + b1) + (b2 + b3);
      unsigned x1 = __builtin_bit_cast(unsigned, __builtin_amdgcn_cvt_pkrtz(b0, b1));
      unsigned y1 = __builtin_bit_cast(unsigned, __builtin_amdgcn_cvt_pkrtz(b2, b3));
      pl32swap(x0, x1);
      pl32swap(y0, y1);
      uintx4 u;
      u[0] = x0; u[1] = y0; u[2] = x1; u[3] = y1;
      paf0[g] = __builtin_bit_cast(half8, u);
    }
    __builtin_amdgcn_s_setprio(1);
#pragma unroll
    for (int dt = 0; dt < 4; ++dt) {
      const _Float16* vrow = ldsVc + (dt * 16 + lo) * 64;
      const half8 vf0 = *(const half8*)(vrow + ((hi ^ sw) * 8));
#pragma unroll
      for (int g = 0; g < 2; ++g)
        acc[g][dt] = __builtin_amdgcn_mfma_f32_16x16x32_f16(
            paf0[g], vf0, acc[g][dt], 0, 0, 0);
    }
    __builtin_amdgcn_s_setprio(0);

    // ---- half B: exp/pack jt 2,3 -> paf1; PV with V chunk 1 -------------
    half8 paf1[2];
#pragma unroll
    for (int g = 0; g < 2; ++g) {
      const float a0 = fast_exp2(st[g][2][0]);
      const float a1 = fast_exp2(st[g][2][1]);
      const float a2 = fast_exp2(st[g][2][2]);
      const float a3 = fast_exp2(st[g][2][3]);
      l_s[g] += (a0 + a1) + (a2 + a3);
      unsigned x0 = __builtin_bit_cast(unsigned, __builtin_amdgcn_cvt_pkrtz(a0, a1));
      unsigned y0 = __builtin_bit_cast(unsigned, __builtin_amdgcn_cvt_pkrtz(a2, a3));
      const float b0 = fast_exp2(st[g][3][0]);
      const float b1 = fast_exp2(st[g][3][1]);
      const float b2 = fast_exp2(st[g][3][2]);
      const float b3 = fast_exp2(st[g][3][3]);
      l_s[g] += (b0 + b1) + (b2 + b3);
      unsigned x1 = __builtin_bit_cast(unsigned, __builtin_amdgcn_cvt_pkrtz(b0, b1));
      unsigned y1 = __builtin_bit_cast(unsigned, __builtin_amdgcn_cvt_pkrtz(b2, b3));
      pl32swap(x0, x1);
      pl32swap(y0, y1);
      uintx4 u;
      u[0] = x0; u[1] = y0; u[2] = x1; u[3] = y1;
      paf1[g] = __builtin_bit_cast(half8, u);
    }
    __builtin_amdgcn_s_setprio(1);
#pragma unroll
    for (int dt = 0; dt < 4; ++dt) {
      const _Float16* vrow = ldsVc + (dt * 16 + lo) * 64;
      const half8 vf1 = *(const half8*)(vrow + (((4 + hi) ^ sw) * 8));
#pragma unroll
      for (int g = 0; g < 2; ++g)
        acc[g][dt] = __builtin_amdgcn_mfma_f32_16x16x32_f16(
            paf1[g], vf1, acc[g][dt], 0, 0, 0);
    }
    __builtin_amdgcn_s_setprio(0);
  }

  // epilogue: reduce l across hi-quads (j coverage), store partials.
  _Float16* obase = Opart + ((size_t)(sp * 16 + bh)) * 4096 * 64;
  float*    lbase = lpart + ((size_t)(sp * 16 + bh)) * 4096;
#pragma unroll
  for (int g = 0; g < 2; ++g) {
    float v = l_s[g];
    v += __shfl_xor(v, 16);
    v += __shfl_xor(v, 32);
    if (hi == 0)
      lbase[qt * 512 + w * 32 + g * 16 + lo] = v;
#pragma unroll
    for (int r = 0; r < 4; ++r) {
      const int q = qt * 512 + w * 32 + g * 16 + hi * 4 + r;
#pragma unroll
      for (int dt = 0; dt < 4; ++dt)
        obase[(size_t)q * 64 + dt * 16 + lo] = (_Float16)acc[g][dt][r];
    }
  }
}

// ---------------- combine 2 splits: O2 fp16 = (O0+O1)/(l0+l1) --------------
__global__ __launch_bounds__(256) void combine_splits(
    const _Float16* __restrict__ Opart, const float* __restrict__ lpart,
    _Float16* __restrict__ O2) {
  const int idx = blockIdx.x * 256 + threadIdx.x;  // [bh:16][q:4096][d4:16]
  const int d0 = (idx & 15) * 4;
  const int q  = (idx >> 4) & 4095;
  const int bh = idx >> 16;
  const int b = bh >> 3, h = bh & 7;
  const half4 a0 = *(const half4*)(Opart + ((size_t)bh * 4096 + q) * 64 + d0);
  const half4 a1 = *(const half4*)(Opart + ((size_t)(16 + bh) * 4096 + q) * 64 + d0);
  const float lsum = lpart[(size_t)bh * 4096 + q] +
                     lpart[(size_t)(16 + bh) * 4096 + q];
  const float inv = 1.f / lsum;
  half4 o;
#pragma unroll
  for (int i = 0; i < 4; ++i)
    o[i] = (_Float16)(((float)a0[i] + (float)a1[i]) * inv);
  *(half4*)(O2 + ((size_t)(b * 4096 + q)) * 512 + h * 64 + d0) = o;
}

// ---------------------------------------------------------------------------
extern "C" void kernel_launch(void* const* d_in, const int* in_sizes, int n_in,
                              void* d_out, int out_size, void* d_ws, size_t ws_size,
                              hipStream_t stream) {
  const float* x     = (const float*)d_in[0];
  const float* pos   = (const float*)d_in[1];
  const float* w_qkv = (const float*)d_in[2];
  const float* w_out = (const float*)d_in[3];
  const float* b_out = (const float*)d_in[4];
  float* out = (float*)d_out;

  char* ws = (char*)d_ws;
  if (ws_size < (size_t)56 * 1024 * 1024) return;

  const size_t MB = 1024 * 1024;
  _Float16* A2x   = (_Float16*)ws;                     // [0,8M) until gemm1
  _Float16* O2    = (_Float16*)ws;                     // [0,8M) after flash
  _Float16* B2qkv = (_Float16*)(ws + 8 * MB);          // [8,11M)
  float2*   CSSN  = (float2*)(ws + 11 * MB);           // [11,13M)
  _Float16* Qb    = (_Float16*)(ws + 13 * MB);         // [13,21M)
  _Float16* Kb    = (_Float16*)(ws + 21 * MB);         // [21,29M)
  _Float16* VT    = (_Float16*)(ws + 29 * MB);         // [29,37M)
  _Float16* Opart = (_Float16*)(ws + 37 * MB);         // [37,53M)
  float*    lpart = (float*)(ws + 53 * MB);            // [53,53.5M)
  _Float16* B2out = (_Float16*)(ws + 54 * MB);         // [54,54.5M)

  prep<<<5376, 256, 0, stream>>>(x, pos, w_qkv, w_out, A2x, CSSN, B2qkv, B2out);
  gemm_qkv_rope<<<dim3(12, 64), 256, 0, stream>>>(A2x, B2qkv, CSSN, Qb, Kb, VT);
  flash_attn<<<dim3(8, 16, 2), 1024, 0, stream>>>(Qb, Kb, VT, Opart, lpart);
  combine_splits<<<4096, 256, 0, stream>>>(Opart, lpart, O2);
  gemm_out_f16<<<dim3(8, 64), 256, 0, stream>>>(O2, B2out, b_out, out);
}